// Round 4
// baseline (464.385 us; speedup 1.0000x reference)
//
#include <hip/hip_runtime.h>
#include <hip/hip_cooperative_groups.h>

// CTC greedy decoder: argmax over V, then per-row unique_consecutive + blank-drop + compact.
// B=64, T=2048, V=512 (fp32 probs, int32 lengths, int32 outputs).
//
// R4: single cooperative kernel (argmax phase -> grid.sync -> compact phase).
//  - Removes one dispatch+gap AND makes the timing decomposable:
//    fused = dur_us - fill(160us) - gap. If fused lands >=~155us it will also
//    surface in rocprof top-5 with its own FETCH_SIZE/hbm_gbps.
//  - Plain (cached) float4 loads again, NOT nontemporal: probs is exactly
//    256 MiB = LLC size; NT loads guaranteed zero LLC residency for probs.
//    Plain loads are the known-good 6.3 TB/s streaming pattern (m13).
//  - argmax structure kept from R3: 4 rows/wave, 16 lanes/row, 8 float4/lane,
//    grid-stride (8 iterations/block) so loads pipeline across iterations.

#define VDIM 512
#define TDIM 2048

namespace cg = cooperative_groups;

__global__ __launch_bounds__(256) void ctc_fused(const float* __restrict__ probs,
                                                 const int* __restrict__ lengths,
                                                 int* __restrict__ out,
                                                 int* __restrict__ out_lengths,
                                                 int nrows, int B) {
    const int tid = threadIdx.x;
    const int w = tid >> 6;          // wave id within block
    const int l = tid & 63;
    const int g = l >> 4;            // row group within wave (0..3)
    const int s = l & 15;            // sublane within row (0..15)

    // ---------------- phase 1: argmax over V for all B*T rows ----------------
    // Each block iteration handles 16 consecutive rows (4 waves x 4 rows).
    const int ngroups = nrows >> 4;              // 8192
    for (int grp = blockIdx.x; grp < ngroups; grp += gridDim.x) {
        const int row = grp * 16 + w * 4 + g;

        const float4* p = (const float4*)(probs + (size_t)row * VDIM);
        float4 v[8];
        #pragma unroll
        for (int j = 0; j < 8; j++) v[j] = p[j * 16 + s];

        // local argmax over 32 elements in ascending-index order
        // (strict > keeps the first occurrence, matching jnp.argmax)
        float bv = v[0].x;
        int bi = s * 4;
        #pragma unroll
        for (int j = 0; j < 8; j++) {
            const int base = j * 64 + s * 4;
            const float4 a = v[j];
            if (j > 0) { if (a.x > bv) { bv = a.x; bi = base; } }
            if (a.y > bv) { bv = a.y; bi = base + 1; }
            if (a.z > bv) { bv = a.z; bi = base + 2; }
            if (a.w > bv) { bv = a.w; bi = base + 3; }
        }

        // butterfly across the 16-lane group; ties -> lower index
        #pragma unroll
        for (int off = 8; off > 0; off >>= 1) {
            float ov = __shfl_xor(bv, off, 16);
            int   oi = __shfl_xor(bi, off, 16);
            if (ov > bv || (ov == bv && oi < bi)) { bv = ov; bi = oi; }
        }

        // 16 consecutive dwords per block-iteration (coalesced)
        if (s == 0) out[row] = bi;
    }

    // tokens (in out[0..nrows)) visible device-wide after this
    cg::this_grid().sync();

    // ---------------- phase 2: per-batch-row compact (blocks 0..B-1) --------
    if (blockIdx.x >= B) return;
    const int b = blockIdx.x;
    const int t0 = tid * 8;
    const int* row = out + (size_t)b * TDIM;

    // load 8 tokens (2x int4) + predecessor (all reads before first barrier;
    // in-place compact is safe)
    int4 lo = ((const int4*)(row + t0))[0];
    int4 hi = ((const int4*)(row + t0))[1];
    int tok[8] = { lo.x, lo.y, lo.z, lo.w, hi.x, hi.y, hi.z, hi.w };
    int prev = (t0 == 0) ? -1 : row[t0 - 1];

    int len = lengths[b];
    if (len < 0) len = 0;
    if (len > TDIM) len = TDIM;

    // thread-local keep flags + exclusive positions
    int pos[8];
    unsigned kb = 0;
    int c = 0;
    #pragma unroll
    for (int j = 0; j < 8; j++) {
        int t = t0 + j;
        int tk = tok[j];
        bool keep = (t < len) & (tk != 0) & (tk != prev);
        pos[j] = c;
        if (keep) { kb |= (1u << j); c++; }
        prev = tk;
    }

    // block exclusive scan: wave shuffle scan + 4-wave LDS combine
    int lane = tid & 63;
    int wid = tid >> 6;
    int incl = c;
    #pragma unroll
    for (int off = 1; off < 64; off <<= 1) {
        int n = __shfl_up(incl, off, 64);
        if (lane >= off) incl += n;
    }
    __shared__ int wsum[4];
    if (lane == 63) wsum[wid] = incl;
    __syncthreads();
    int wbase = 0;
    #pragma unroll
    for (int ww = 0; ww < 4; ww++) {
        int ssum = wsum[ww];
        if (ww < wid) wbase += ssum;
    }
    int excl = wbase + incl - c;
    int total = wsum[0] + wsum[1] + wsum[2] + wsum[3];

    // scatter kept tokens to [0, total)
    int* orow = out + (size_t)b * TDIM;
    #pragma unroll
    for (int j = 0; j < 8; j++) {
        if ((kb >> j) & 1u) orow[excl + pos[j]] = tok[j];
    }
    // zero-fill [total, T)
    for (int t = total + tid; t < TDIM; t += 256) orow[t] = 0;

    if (tid == 0) out_lengths[b] = total;
}

extern "C" void kernel_launch(void* const* d_in, const int* in_sizes, int n_in,
                              void* d_out, int out_size, void* d_ws, size_t ws_size,
                              hipStream_t stream) {
    (void)d_ws; (void)ws_size; (void)n_in; (void)out_size;
    const float* probs = (const float*)d_in[0];
    const int* lengths = (const int*)d_in[1];
    int* out = (int*)d_out;

    int B = in_sizes[1];                 // 64
    int nrows = in_sizes[0] / VDIM;      // B*T = 131072
    int* out_lengths = out + nrows;

    // 1024 blocks x 256 threads = 4 blocks/CU (16 waves/CU) -> co-resident,
    // safe for cooperative launch. 8192 row-groups / 1024 = 8 iters/block.
    void* args[] = { (void*)&probs, (void*)&lengths, (void*)&out,
                     (void*)&out_lengths, (void*)&nrows, (void*)&B };
    hipLaunchCooperativeKernel((void*)ctc_fused, dim3(1024), dim3(256),
                               args, 0, stream);
}

// Round 5
// 353.902 us; speedup vs baseline: 1.3122x; 1.3122x over previous
//
#include <hip/hip_runtime.h>

// CTC greedy decoder: argmax over V, then per-row unique_consecutive + blank-drop + compact.
// B=64, T=2048, V=512 (fp32 probs, int32 lengths, int32 outputs).
//
// R5: two plain kernels again (cooperative launch cost ~110 us of per-iteration
// overhead in R4 -- reverted). Single variable vs R3: argmax stages each block's
// 16 rows (32 KB) into LDS with __builtin_amdgcn_global_load_lds (16 B/lane,
// async direct-to-LDS, no VGPR round trip), then computes the argmax from LDS.
// R4's counters showed the old path ran at 1.4 TB/s effective with VALU 3.5%,
// occupancy 45%, zero conflicts, HBM+LLC pipes idle -- and VGPR_Count=32 (the
// compiler serialized the in-register load chain). This tests the only untried
// memory path; multi-block residency (32 KB LDS -> ~5 blocks/CU) overlaps one
// block's staging with another's compute.

#define VDIM 512
#define TDIM 2048

#define GLB(p) ((const __attribute__((address_space(1))) void*)(p))
#define LDS(p) ((__attribute__((address_space(3))) void*)(p))

// Block = 256 threads = 4 waves; block handles 16 consecutive rows.
// Wave w stages rows [w*4, w*4+4) (8 KB = 8 x 1KB chunks) into LDS, then its
// four 16-lane groups g each argmax one row. Lane s of a group reads float4s
// j*16+s of the row (ascending index order -> strict > keeps first occurrence,
// matching jnp.argmax).
__global__ __launch_bounds__(256) void argmax_rows(const float* __restrict__ probs,
                                                   int* __restrict__ tokens,
                                                   int nrows) {
    __shared__ float tile[16 * VDIM];            // 32 KB
    const int tid = threadIdx.x;
    const int w = tid >> 6;          // wave id within block
    const int l = tid & 63;
    const int g = l >> 4;            // row group within wave (0..3)
    const int s = l & 15;            // sublane within row (0..15)
    const int row0 = blockIdx.x * 16;
    if (row0 >= nrows) return;       // whole block OOB (uniform) -- safe

    // ---- stage 32 KB block-tile: wave w copies its 8 KB as 8 async 1-KB chunks
    // LDS dest must be wave-uniform (HW adds lane*16); global src is per-lane.
    {
        const float* gsrc = probs + (size_t)row0 * VDIM + (size_t)w * 2048;
        float* lbase = tile + w * 2048;
        #pragma unroll
        for (int j = 0; j < 8; j++) {
            __builtin_amdgcn_global_load_lds(GLB(gsrc + j * 256 + l * 4),
                                             LDS(lbase + j * 256), 16, 0, 0);
        }
    }
    __syncthreads();                 // drains vmcnt before barrier -> tile ready

    // ---- argmax of row (w*4+g) from LDS
    const float4* lrow = (const float4*)(tile + (w * 4 + g) * VDIM);
    float4 v[8];
    #pragma unroll
    for (int j = 0; j < 8; j++) v[j] = lrow[j * 16 + s];

    float bv = v[0].x;
    int bi = s * 4;
    #pragma unroll
    for (int j = 0; j < 8; j++) {
        const int base = j * 64 + s * 4;
        const float4 a = v[j];
        if (j > 0) { if (a.x > bv) { bv = a.x; bi = base; } }
        if (a.y > bv) { bv = a.y; bi = base + 1; }
        if (a.z > bv) { bv = a.z; bi = base + 2; }
        if (a.w > bv) { bv = a.w; bi = base + 3; }
    }

    // butterfly across the 16-lane group; ties -> lower index (first occurrence)
    #pragma unroll
    for (int off = 8; off > 0; off >>= 1) {
        float ov = __shfl_xor(bv, off, 16);
        int   oi = __shfl_xor(bi, off, 16);
        if (ov > bv || (ov == bv && oi < bi)) { bv = ov; bi = oi; }
    }

    // 16 consecutive dwords per block (coalesced)
    const int row = row0 + w * 4 + g;
    if (s == 0 && row < nrows) tokens[row] = bi;
}

// One block (256 threads) per batch row; 8 tokens/thread over T=2048.
// keep = (t < len) && (tok != 0) && (tok != prev); prefix-scan; compact left; zero tail.
// All global READS happen before the first __syncthreads (which drains vmcnt on
// gfx950), so the kernel is safe when `tokens` aliases `out` (in-place compact).
__global__ __launch_bounds__(256) void ctc_compact(const int* __restrict__ tokens,
                                                   const int* __restrict__ lengths,
                                                   int* __restrict__ out,
                                                   int* __restrict__ out_lengths) {
    const int b = blockIdx.x;
    const int tid = threadIdx.x;
    const int t0 = tid * 8;

    const int* row = tokens + (size_t)b * TDIM;

    // load 8 tokens (2x int4) + predecessor
    int4 lo = ((const int4*)(row + t0))[0];
    int4 hi = ((const int4*)(row + t0))[1];
    int tok[8] = { lo.x, lo.y, lo.z, lo.w, hi.x, hi.y, hi.z, hi.w };
    int prev = (t0 == 0) ? -1 : row[t0 - 1];

    int len = lengths[b];
    if (len < 0) len = 0;
    if (len > TDIM) len = TDIM;

    // thread-local keep flags + exclusive positions
    int pos[8];
    unsigned kb = 0;
    int c = 0;
    #pragma unroll
    for (int j = 0; j < 8; j++) {
        int t = t0 + j;
        int tk = tok[j];
        bool keep = (t < len) & (tk != 0) & (tk != prev);
        pos[j] = c;
        if (keep) { kb |= (1u << j); c++; }
        prev = tk;
    }

    // block exclusive scan: wave shuffle scan + 4-wave LDS combine
    int lane = tid & 63;
    int wid = tid >> 6;
    int incl = c;
    #pragma unroll
    for (int off = 1; off < 64; off <<= 1) {
        int n = __shfl_up(incl, off, 64);
        if (lane >= off) incl += n;
    }
    __shared__ int wsum[4];
    if (lane == 63) wsum[wid] = incl;
    __syncthreads();
    int wbase = 0;
    #pragma unroll
    for (int ww = 0; ww < 4; ww++) {
        int ssum = wsum[ww];
        if (ww < wid) wbase += ssum;
    }
    int excl = wbase + incl - c;
    int total = wsum[0] + wsum[1] + wsum[2] + wsum[3];

    // scatter kept tokens to [0, total)
    int* orow = out + (size_t)b * TDIM;
    #pragma unroll
    for (int j = 0; j < 8; j++) {
        if ((kb >> j) & 1u) orow[excl + pos[j]] = tok[j];
    }
    // zero-fill [total, T)
    for (int t = total + tid; t < TDIM; t += 256) orow[t] = 0;

    if (tid == 0) out_lengths[b] = total;
}

extern "C" void kernel_launch(void* const* d_in, const int* in_sizes, int n_in,
                              void* d_out, int out_size, void* d_ws, size_t ws_size,
                              hipStream_t stream) {
    (void)d_ws; (void)ws_size; (void)n_in; (void)out_size;
    const float* probs = (const float*)d_in[0];
    const int* lengths = (const int*)d_in[1];
    int* out = (int*)d_out;

    const int B = in_sizes[1];              // 64
    const int nrows = in_sizes[0] / VDIM;   // B*T = 131072

    // tokens scratch aliases d_out (in-place): argmax fills out[0..B*T) with
    // per-(b,t) argmax tokens, ctc_compact then compacts each row in place.
    int* tokens = out;

    // 16 rows per 256-thread block (4 waves x 4 rows staged through 32 KB LDS)
    argmax_rows<<<(nrows + 15) / 16, 256, 0, stream>>>(probs, tokens, nrows);
    ctc_compact<<<B, 256, 0, stream>>>(tokens, lengths, out, out + nrows);
}

// Round 6
// 311.572 us; speedup vs baseline: 1.4905x; 1.1359x over previous
//
#include <hip/hip_runtime.h>

// CTC greedy decoder: argmax over V, then per-row unique_consecutive + blank-drop + compact.
// B=64, T=2048, V=512 (fp32 probs, int32 lengths, int32 outputs).
//
// R6 = R3 (best known, 330.6 us) + LENGTH-SKIP in argmax.
// Semantics: reference masks tokens with (t < lengths[b]) BEFORE dedup/compact,
// and zero-pads the output. So argmax for t >= lengths[b] is dead work: compact's
// keep-mask ignores those token slots (stale poison there is provably never read
// into the output: scatter copies only kept positions, zero-fill covers the rest,
// and a garbage `prev` at a block boundary only influences keep of positions that
// are themselves masked). lengths ~ U[0,2048) => ~half the 256 MiB is skipped.
// Blocks above the cutoff exit before issuing any vector load.

#define VDIM 512
#define TDIM 2048

typedef float vfloat4 __attribute__((ext_vector_type(4)));

// Block = 256 threads = 4 waves; block handles 16 consecutive rows (same batch b,
// since 16 | 2048). Lane (g,s): g = row-within-wave, s = 16-lane sublane.
// Lane s of a row reads float4s j*16+s (ascending index order -> strict >
// comparisons keep the first occurrence, matching jnp.argmax).
__global__ __launch_bounds__(256) void argmax_rows(const float* __restrict__ probs,
                                                   const int* __restrict__ lengths,
                                                   int* __restrict__ tokens,
                                                   int nrows) {
    const int row0 = blockIdx.x * 16;
    if (row0 >= nrows) return;           // uniform

    // length-skip: all 16 rows of this block share batch b
    const int b = row0 >> 11;            // row0 / TDIM
    const int t0 = row0 & (TDIM - 1);
    if (t0 >= lengths[b]) return;        // uniform; dead rows, tokens slots unused

    const int tid = threadIdx.x;
    const int w = tid >> 6;              // wave id within block
    const int l = tid & 63;
    const int g = l >> 4;                // row group within wave (0..3)
    const int s = l & 15;                // sublane within row (0..15)
    const int row = row0 + w * 4 + g;

    const vfloat4* p = (const vfloat4*)(probs + (size_t)row * VDIM);

    // 8 independent nontemporal 16B loads (memory-level parallelism).
    vfloat4 v[8];
    #pragma unroll
    for (int j = 0; j < 8; j++) {
        v[j] = __builtin_nontemporal_load(&p[j * 16 + s]);
    }

    // Local argmax over 32 elements in ascending-index order (strict > keeps first).
    float bv = v[0].x;
    int bi = s * 4;
    #pragma unroll
    for (int j = 0; j < 8; j++) {
        const int base = j * 64 + s * 4;
        const vfloat4 a = v[j];
        if (j > 0) { if (a.x > bv) { bv = a.x; bi = base; } }
        if (a.y > bv) { bv = a.y; bi = base + 1; }
        if (a.z > bv) { bv = a.z; bi = base + 2; }
        if (a.w > bv) { bv = a.w; bi = base + 3; }
    }

    // Butterfly across the 16-lane group; ties -> lower index (first occurrence).
    #pragma unroll
    for (int off = 8; off > 0; off >>= 1) {
        float ov = __shfl_xor(bv, off, 16);
        int   oi = __shfl_xor(bi, off, 16);
        if (ov > bv || (ov == bv && oi < bi)) { bv = ov; bi = oi; }
    }

    // Lanes s==0 of the 4 groups write 4 consecutive dwords (coalesced).
    if (s == 0) tokens[row] = bi;
}

// One block (256 threads) per batch row; 8 tokens/thread over T=2048.
// keep = (t < len) && (tok != 0) && (tok != prev); prefix-scan; compact left; zero tail.
// All global READS happen before the first __syncthreads (which drains vmcnt on
// gfx950), so the kernel is safe when `tokens` aliases `out` (in-place compact).
// Token slots at t >= len may hold stale poison (length-skip); keep masks them.
__global__ __launch_bounds__(256) void ctc_compact(const int* __restrict__ tokens,
                                                   const int* __restrict__ lengths,
                                                   int* __restrict__ out,
                                                   int* __restrict__ out_lengths) {
    const int b = blockIdx.x;
    const int tid = threadIdx.x;
    const int t0 = tid * 8;

    const int* row = tokens + (size_t)b * TDIM;

    // load 8 tokens (2x int4) + predecessor
    int4 lo = ((const int4*)(row + t0))[0];
    int4 hi = ((const int4*)(row + t0))[1];
    int tok[8] = { lo.x, lo.y, lo.z, lo.w, hi.x, hi.y, hi.z, hi.w };
    int prev = (t0 == 0) ? -1 : row[t0 - 1];

    int len = lengths[b];
    if (len < 0) len = 0;
    if (len > TDIM) len = TDIM;

    // thread-local keep flags + exclusive positions
    int pos[8];
    unsigned kb = 0;
    int c = 0;
    #pragma unroll
    for (int j = 0; j < 8; j++) {
        int t = t0 + j;
        int tk = tok[j];
        bool keep = (t < len) & (tk != 0) & (tk != prev);
        pos[j] = c;
        if (keep) { kb |= (1u << j); c++; }
        prev = tk;
    }

    // block exclusive scan: wave shuffle scan + 4-wave LDS combine
    int lane = tid & 63;
    int wid = tid >> 6;
    int incl = c;
    #pragma unroll
    for (int off = 1; off < 64; off <<= 1) {
        int n = __shfl_up(incl, off, 64);
        if (lane >= off) incl += n;
    }
    __shared__ int wsum[4];
    if (lane == 63) wsum[wid] = incl;
    __syncthreads();
    int wbase = 0;
    #pragma unroll
    for (int ww = 0; ww < 4; ww++) {
        int ssum = wsum[ww];
        if (ww < wid) wbase += ssum;
    }
    int excl = wbase + incl - c;
    int total = wsum[0] + wsum[1] + wsum[2] + wsum[3];

    // scatter kept tokens to [0, total)
    int* orow = out + (size_t)b * TDIM;
    #pragma unroll
    for (int j = 0; j < 8; j++) {
        if ((kb >> j) & 1u) orow[excl + pos[j]] = tok[j];
    }
    // zero-fill [total, T)
    for (int t = total + tid; t < TDIM; t += 256) orow[t] = 0;

    if (tid == 0) out_lengths[b] = total;
}

extern "C" void kernel_launch(void* const* d_in, const int* in_sizes, int n_in,
                              void* d_out, int out_size, void* d_ws, size_t ws_size,
                              hipStream_t stream) {
    (void)d_ws; (void)ws_size; (void)n_in; (void)out_size;
    const float* probs = (const float*)d_in[0];
    const int* lengths = (const int*)d_in[1];
    int* out = (int*)d_out;

    const int B = in_sizes[1];              // 64
    const int nrows = in_sizes[0] / VDIM;   // B*T = 131072

    // tokens scratch aliases d_out (in-place): argmax fills out[0..B*T) for
    // t < lengths[b]; ctc_compact then compacts each row in place.
    int* tokens = out;

    // 16 rows per 256-thread block (4 waves x 4 rows/wave)
    argmax_rows<<<(nrows + 15) / 16, 256, 0, stream>>>(probs, lengths, tokens, nrows);
    ctc_compact<<<B, 256, 0, stream>>>(tokens, lengths, out, out + nrows);
}